// Round 12
// baseline (310.694 us; speedup 1.0000x reference)
//
#include <hip/hip_runtime.h>

// StandardAttention: B=2,S=2048,D=1024,H=16,DQK=DV=64. fp32 in/out, bf16 MFMA inside.
// Workspace layout (56 MB):
//   xb  [4096][1024] bf16           8 MB   (dead after gemm_qkv -> heavy half1 fp32 partials Ph1)
//   WT  [4][1024][1024] bf16 (W^T)  8 MB   (z=0 dead after gemm_qkv -> first 256KB = lsum Lb)
//   Q,K [B][H][S][64] bf16          16 MB  (Q pre-scaled by 0.125*log2(e))
//   Vb  (unused slot)               8 MB   (heavy half0 fp32 partials Ph0)
//   Vp  [B][H][64][S] bf16          8 MB
//   AO  [B][S][1024] bf16           8 MB   (heavy-pair flags live in AO heavy rows, zeroed by prep)
//
// R2: BK=64. R7: split-K heavy flash. R8: static-dbuf 1-barrier GEMMs. R10: prep fusion.
// R11: flash counted-vmcnt 3-buffer pipeline (166.8us).
// R12: merge kernel ELIMINATED -> last-writer-merges in flash epilogue. Each heavy pair
//   (bh,qi) has a 4B ticket at AO[pair row0, h*64] (its own output region; overwritten by
//   the merge itself). prep zeroes the 256 tickets each iter. Heavy block: partials ->
//   threadfence (release) -> atomicAdd ticket; second arrival threadfence (acquire) and
//   merges (P0+P1)/(l0+l1) into AO. Device-scope atomics/fences per G16; no spinning.

typedef float  f32x4  __attribute__((ext_vector_type(4)));
typedef __bf16 bf16x8 __attribute__((ext_vector_type(8)));

__device__ __forceinline__ unsigned short f2bf(float f) {
    __bf16 h = (__bf16)f;
    return __builtin_bit_cast(unsigned short, h);
}

// async global->LDS, 16B per lane; lds base wave-uniform (HW: base + lane*16)
__device__ __forceinline__ void gld16(unsigned short* lds, const unsigned short* g) {
    __builtin_amdgcn_global_load_lds(
        (const __attribute__((address_space(1))) void*)g,
        (__attribute__((address_space(3))) void*)lds, 16, 0, 0);
}

// ---------------- prep: castx (blocks 0..4095) + wtrans (4096..5119) + flag zeroing -----
__global__ __launch_bounds__(256) void prep(const float* __restrict__ x,
                                            const float* __restrict__ W0,
                                            const float* __restrict__ W1,
                                            const float* __restrict__ W2,
                                            const float* __restrict__ W3,
                                            unsigned short* __restrict__ xb,
                                            unsigned short* __restrict__ WT,
                                            unsigned short* __restrict__ AO) {
    __shared__ float T[64][65];
    const int blk = blockIdx.x;
    const int tid = threadIdx.x;
    if (blk < 4096) {
        size_t i = ((size_t)blk * 256 + tid) * 4;
        float4 v = *(const float4*)(x + i);
        ushort4 o;
        o.x = f2bf(v.x); o.y = f2bf(v.y); o.z = f2bf(v.z); o.w = f2bf(v.w);
        *(ushort4*)(xb + i) = o;
        if (blk == 0) {
            // zero the 256 heavy-pair merge tickets (4B each, inside AO heavy rows)
            const int bh = tid >> 3, qi8 = tid & 7;
            const int bz = bh >> 4, h = bh & 15;
            *(unsigned int*)(AO + (((size_t)(bz * 2048 + (qi8 + 8) * 128)) << 10) + h * 64) = 0u;
        }
        return;
    }
    const int t = blk - 4096;
    const int z = t >> 8;
    const int k0 = ((t >> 4) & 15) * 64, n0 = (t & 15) * 64;
    const float* W = (z == 0) ? W0 : (z == 1) ? W1 : (z == 2) ? W2 : W3;
#pragma unroll
    for (int i = 0; i < 4; i++) {
        int c = tid + i * 256;
        int r = c >> 4, col = (c & 15) * 4;
        float4 v = *(const float4*)(W + (size_t)(k0 + r) * 1024 + n0 + col);
        T[r][col] = v.x; T[r][col + 1] = v.y; T[r][col + 2] = v.z; T[r][col + 3] = v.w;
    }
    __syncthreads();
    unsigned short* out = WT + (size_t)z * 1024 * 1024;
#pragma unroll
    for (int i = 0; i < 2; i++) {
        int c = tid + i * 256;
        int nr = c >> 3, koff = (c & 7) * 8;
        union { unsigned short us[8]; uint4 v; } pk;
#pragma unroll
        for (int j = 0; j < 8; j++) pk.us[j] = f2bf(T[koff + j][nr]);
        *(uint4*)(out + (size_t)(n0 + nr) * 1024 + k0 + koff) = pk.v;
    }
}

// ---------------- QKV GEMM: [4096][1024] x WT^T per z; BK=64, static dbuf, 1 barrier ----
__global__ __launch_bounds__(256) void gemm_qkv(const unsigned short* __restrict__ A,
                                                const unsigned short* __restrict__ WTall,
                                                unsigned short* __restrict__ outq,
                                                unsigned short* __restrict__ Vp) {
    __shared__ unsigned short As0[128 * 64];
    __shared__ unsigned short Bs0[128 * 64];
    __shared__ unsigned short As1[128 * 64];
    __shared__ unsigned short Bs1[128 * 64];
    const int tid = threadIdx.x;
    const int w = tid >> 6, lane = tid & 63, quad = lane >> 4, ln = lane & 15;

    const int blk = blockIdx.x;
    const int n0 = ((blk >> 3) & 7) * 128;
    const int g  = ((blk >> 6) << 3) | (blk & 7);   // 0..95 = z*32+m
    const int z  = g >> 5;
    const int m0 = (g & 31) * 128;

    const unsigned short* BT = WTall + (size_t)z * (1024 * 1024);
    const float scl = (z == 0) ? 0.180336878f : 1.0f;
    const bool swp = (z < 2);

    const int lr8 = lane >> 3;                      // row within 8-row staging group
    const int lc8 = ((lane & 7) ^ lr8) * 8;         // XOR-swizzled source chunk (elems)
    const int fsw = (quad ^ (ln & 7)) * 8;          // swizzled frag-read chunk (elems)

    const f32x4 z4 = {0.f, 0.f, 0.f, 0.f};
    f32x4 acc[4][4];
#pragma unroll
    for (int i = 0; i < 4; i++)
#pragma unroll
        for (int j = 0; j < 4; j++) acc[i][j] = z4;

    const int wm = (w & 1) * 64, wn = (w >> 1) * 64;
    const int Rb = w * 32;                          // staging row base for this wave

#define QKV_STAGE(Ad, Bd, kk)                                                              \
    {                                                                                      \
        _Pragma("unroll")                                                                  \
        for (int s = 0; s < 4; s++) {                                                      \
            gld16(Ad + (Rb + s * 8) * 64, A  + (size_t)(m0 + Rb + s * 8 + lr8) * 1024 + (kk) + lc8); \
            gld16(Bd + (Rb + s * 8) * 64, BT + (size_t)(n0 + Rb + s * 8 + lr8) * 1024 + (kk) + lc8); \
        }                                                                                  \
    }

#define QKV_COMPUTE(Ad, Bd)                                                                \
    {                                                                                      \
        _Pragma("unroll")                                                                  \
        for (int ks = 0; ks < 2; ks++) {                                                   \
            const int co = fsw ^ (ks * 32);                                                \
            bf16x8 af[4], bfr[4];                                                          \
            _Pragma("unroll")                                                              \
            for (int t = 0; t < 4; t++)                                                    \
                af[t] = *(const bf16x8*)&Ad[(wm + t * 16 + ln) * 64 + co];                 \
            _Pragma("unroll")                                                              \
            for (int t = 0; t < 4; t++)                                                    \
                bfr[t] = *(const bf16x8*)&Bd[(wn + t * 16 + ln) * 64 + co];                \
            if (swp) {                                                                     \
                _Pragma("unroll")                                                          \
                for (int tm = 0; tm < 4; tm++)                                             \
                    _Pragma("unroll")                                                      \
                    for (int tn = 0; tn < 4; tn++)                                         \
                        acc[tm][tn] = __builtin_amdgcn_mfma_f32_16x16x32_bf16(             \
                            bfr[tn], af[tm], acc[tm][tn], 0, 0, 0);                        \
            } else {                                                                       \
                _Pragma("unroll")                                                          \
                for (int tm = 0; tm < 4; tm++)                                             \
                    _Pragma("unroll")                                                      \
                    for (int tn = 0; tn < 4; tn++)                                         \
                        acc[tm][tn] = __builtin_amdgcn_mfma_f32_16x16x32_bf16(             \
                            af[tm], bfr[tn], acc[tm][tn], 0, 0, 0);                        \
            }                                                                              \
        }                                                                                  \
    }

    QKV_STAGE(As0, Bs0, 0);
    for (int k0 = 0; k0 < 1024; k0 += 128) {
        __syncthreads();                          // publishes buf0 (drains its staging)
        if (k0 + 64 < 1024) QKV_STAGE(As1, Bs1, k0 + 64);
        QKV_COMPUTE(As0, Bs0);
        __syncthreads();                          // publishes buf1
        if (k0 + 128 < 1024) QKV_STAGE(As0, Bs0, k0 + 128);
        if (k0 + 64 < 1024) QKV_COMPUTE(As1, Bs1);
    }
#undef QKV_STAGE
#undef QKV_COMPUTE

    if (swp) {
        // acc[tm][tn] = D^T block: lane ln -> s-row, regs -> 4 consecutive d
#pragma unroll
        for (int tm = 0; tm < 4; tm++)
#pragma unroll
            for (int tn = 0; tn < 4; tn++) {
                int mg = m0 + wm + tm * 16 + ln;            // s row (global among 4096)
                int nb = n0 + wn + tn * 16 + quad * 4;      // d col base
                int b = mg >> 11, s = mg & 2047, h = nb >> 6, dd = nb & 63;
                ushort4 o;
                o.x = f2bf(acc[tm][tn][0] * scl);
                o.y = f2bf(acc[tm][tn][1] * scl);
                o.z = f2bf(acc[tm][tn][2] * scl);
                o.w = f2bf(acc[tm][tn][3] * scl);
                size_t zoff = (size_t)z * (4096 * 1024);
                *(ushort4*)(outq + zoff + (((size_t)(b * 16 + h) * 2048 + s) << 6) + dd) = o;
            }
    } else {
        // V: normal D block: lane ln -> d, regs -> 4 consecutive s = one Vp permute group
#pragma unroll
        for (int tm = 0; tm < 4; tm++)
#pragma unroll
            for (int tn = 0; tn < 4; tn++) {
                int mg = m0 + wm + tm * 16 + quad * 4;      // s base (r spans 4)
                int ng = n0 + wn + tn * 16 + ln;            // d
                int b = mg >> 11, h = ng >> 6, dd = ng & 63;
                int sblk = (mg & 2047) & ~63;
                int cb = tm >> 1, t16 = tm & 1;
                int pp = cb * 32 + quad * 8 + t16 * 4;
                ushort4 o;
                o.x = f2bf(acc[tm][tn][0]);
                o.y = f2bf(acc[tm][tn][1]);
                o.z = f2bf(acc[tm][tn][2]);
                o.w = f2bf(acc[tm][tn][3]);
                *(ushort4*)(Vp + ((size_t)(b * 16 + h) * 64 + dd) * 2048 + sblk + pp) = o;
            }
    }
}

// ---------------- out-proj GEMM: out[4096][1024] = AO @ WoT^T, 128x128, static dbuf ----
__global__ __launch_bounds__(256) void gemm_o(const unsigned short* __restrict__ A,
                                              const unsigned short* __restrict__ BT,
                                              float* __restrict__ outf) {
    __shared__ unsigned short As0[128 * 64];
    __shared__ unsigned short Bs0[128 * 64];
    __shared__ unsigned short As1[128 * 64];
    __shared__ unsigned short Bs1[128 * 64];
    const int tid = threadIdx.x;
    const int w = tid >> 6, lane = tid & 63, quad = lane >> 4, ln = lane & 15;

    const int blk = blockIdx.x;
    const int n0 = ((blk >> 3) & 7) * 128;
    const int m0 = (((blk >> 6) << 3) | (blk & 7)) * 128;   // 0..31 tiles

    const int lr8 = lane >> 3;
    const int lc8 = ((lane & 7) ^ lr8) * 8;
    const int fsw = (quad ^ (ln & 7)) * 8;

    const f32x4 z4 = {0.f, 0.f, 0.f, 0.f};
    f32x4 acc[4][4];
#pragma unroll
    for (int i = 0; i < 4; i++)
#pragma unroll
        for (int j = 0; j < 4; j++) acc[i][j] = z4;

    const int wm = (w & 1) * 64, wn = (w >> 1) * 64;
    const int Rb = w * 32;

#define O_STAGE(Ad, Bd, kk)                                                                \
    {                                                                                      \
        _Pragma("unroll")                                                                  \
        for (int s = 0; s < 4; s++) {                                                      \
            gld16(Ad + (Rb + s * 8) * 64, A  + (size_t)(m0 + Rb + s * 8 + lr8) * 1024 + (kk) + lc8); \
            gld16(Bd + (Rb + s * 8) * 64, BT + (size_t)(n0 + Rb + s * 8 + lr8) * 1024 + (kk) + lc8); \
        }                                                                                  \
    }

#define O_COMPUTE(Ad, Bd)                                                                  \
    {                                                                                      \
        _Pragma("unroll")                                                                  \
        for (int ks = 0; ks < 2; ks++) {                                                   \
            const int co = fsw ^ (ks * 32);                                                \
            bf16x8 af[4], bfr[4];                                                          \
            _Pragma("unroll")                                                              \
            for (int t = 0; t < 4; t++)                                                    \
                af[t] = *(const bf16x8*)&Ad[(wm + t * 16 + ln) * 64 + co];                 \
            _Pragma("unroll")                                                              \
            for (int t = 0; t < 4; t++)                                                    \
                bfr[t] = *(const bf16x8*)&Bd[(wn + t * 16 + ln) * 64 + co];                \
            _Pragma("unroll")                                                              \
            for (int tm = 0; tm < 4; tm++)                                                 \
                _Pragma("unroll")                                                          \
                for (int tn = 0; tn < 4; tn++)                                             \
                    acc[tm][tn] = __builtin_amdgcn_mfma_f32_16x16x32_bf16(                 \
                        bfr[tn], af[tm], acc[tm][tn], 0, 0, 0);                            \
        }                                                                                  \
    }

    O_STAGE(As0, Bs0, 0);
    for (int k0 = 0; k0 < 1024; k0 += 128) {
        __syncthreads();
        if (k0 + 64 < 1024) O_STAGE(As1, Bs1, k0 + 64);
        O_COMPUTE(As0, Bs0);
        __syncthreads();
        if (k0 + 128 < 1024) O_STAGE(As0, Bs0, k0 + 128);
        if (k0 + 64 < 1024) O_COMPUTE(As1, Bs1);
    }
#undef O_STAGE
#undef O_COMPUTE

    // D^T blocks: lane ln -> output row, reg quad -> 4 consecutive cols -> float4 stores
#pragma unroll
    for (int tm = 0; tm < 4; tm++)
#pragma unroll
        for (int tn = 0; tn < 4; tn++) {
            int mg = m0 + wm + tm * 16 + ln;
            int nb = n0 + wn + tn * 16 + quad * 4;
            *(f32x4*)(outf + (size_t)mg * 1024 + nb) = acc[tm][tn];
        }
}

// ---------------- flash attention (split-K, counted-vmcnt 3-buffer, fused merge) --------
// Slot decode: bh = blk&31, s = blk>>5 (0..23).
//   s<8:    light q-tile qi=s, full k range, normalize, write AO.
//   s>=8:   heavy q-tile qi=15-((s-8)&7), half=(s-8)>>3; fp32 partials to ws; the SECOND
//           block of each pair to finish (atomic ticket in AO) merges into AO.
// R11 pipeline: 3 staging buffers, counted s_waitcnt vmcnt(2), sched_barrier after s_barrier.
__global__ __launch_bounds__(512, 4) void flash(const unsigned short* __restrict__ Qb,
                                                const unsigned short* __restrict__ Kb,
                                                const unsigned short* __restrict__ Vpb,
                                                unsigned short* __restrict__ AO,
                                                float* __restrict__ Ph0,
                                                float* __restrict__ Ph1,
                                                float* __restrict__ Lb) {
    __shared__ __align__(16) unsigned short Ks0[64 * 64];
    __shared__ __align__(16) unsigned short Vs0[64 * 64];
    __shared__ __align__(16) unsigned short Ks1[64 * 64];
    __shared__ __align__(16) unsigned short Vs1[64 * 64];
    __shared__ __align__(16) unsigned short Ks2[64 * 64];
    __shared__ __align__(16) unsigned short Vs2[64 * 64];
    __shared__ unsigned int s_last;
    const int tid = threadIdx.x, w = tid >> 6, lane = tid & 63;
    const int qd = lane >> 4, ln = lane & 15;
    const int lr = lane >> 3;                  // row-within-8 for staging
    const int lchunk = (lane & 7) ^ lr;        // swizzled source 16B-chunk
    const int psw = (qd ^ (ln & 7)) * 8;       // swizzled read chunk offset (elems)

    const int blk = blockIdx.x;
    const int bh = blk & 31;
    const int s  = blk >> 5;                   // 0..23
    int qi, kstart, kend, half;
    bool heavy;
    if (s < 8) {
        qi = s; kstart = 0; kend = (qi + 1) * 128; half = 0; heavy = false;
    } else {
        int t = s - 8; half = t >> 3; qi = 15 - (t & 7); heavy = true;
        int mid = (qi + 1) * 64;
        kstart = half ? mid : 0;
        kend   = half ? (qi + 1) * 128 : mid;
    }
    const int qt0 = qi * 128;

    const unsigned short* Kg = Kb  + (size_t)bh * 2048 * 64;
    const unsigned short* Vg = Vpb + (size_t)bh * 64 * 2048;

    // Q fragment (B-operand of S^T MFMA): lane ln holds Q[qt0+w*16+ln][qd*8+j]
    bf16x8 aq[2];
    {
        const unsigned short* Qrow = Qb + ((size_t)bh * 2048 + qt0 + w * 16 + ln) * 64 + qd * 8;
        aq[0] = *(const bf16x8*)(Qrow);
        aq[1] = *(const bf16x8*)(Qrow + 32);
    }

    const f32x4 z4 = {0.f, 0.f, 0.f, 0.f};
    f32x4 Oc[4];
#pragma unroll
    for (int td = 0; td < 4; td++) Oc[td] = z4;
    float lsum = 0.f;

    const int qrow = qt0 + w * 16 + ln;   // lane's q row (S^T: q indexed by ln)
    const int qmin = qt0 + w * 16;
    const int qmax = qmin + 15;

    // stage(KD,VD, kk): wave w fills K rows [w*8,w*8+8) and Vp d-rows [w*8,w*8+8) (2 gld16)
#define FLASH_STAGE(KD, VD, kk)                                                          \
    {                                                                                    \
        const unsigned short* kg = Kg + (size_t)((kk) + w * 8 + lr) * 64 + lchunk * 8;   \
        gld16(&KD[(w * 8) * 64], kg);                                                    \
        const unsigned short* vg = Vg + (size_t)(w * 8 + lr) * 2048 + (kk) + lchunk * 8; \
        gld16(&VD[(w * 8) * 64], vg);                                                    \
    }

    // counted-vmcnt barrier: stage(t) complete; stage(t+1) (2 loads) may stay in flight
#define FLASH_SYNC(more)                                                                 \
    {                                                                                    \
        if (more) { asm volatile("s_waitcnt vmcnt(2)" ::: "memory"); }                   \
        else      { asm volatile("s_waitcnt vmcnt(0)" ::: "memory"); }                   \
        __builtin_amdgcn_s_barrier();                                                    \
        __builtin_amdgcn_sched_barrier(0);                                               \
    }

    // full tile compute from buffers (KD,VD) at k-offset kk (wave-uniform skip)
#define FLASH_TILE(KD, VD, kk)                                                           \
    if ((kk) <= qmax) {                                                                  \
        f32x4 sc[4];                                                                     \
        _Pragma("unroll")                                                                \
        for (int t = 0; t < 4; t++) {                                                    \
            sc[t] = z4;                                                                  \
            if ((kk) + t * 16 <= qmax) {                                                 \
                int off = (t * 16 + ln) * 64 + psw;                                      \
                bf16x8 bk0 = *(const bf16x8*)&KD[off];                                   \
                bf16x8 bk1 = *(const bf16x8*)&KD[off ^ 32];                              \
                sc[t] = __builtin_amdgcn_mfma_f32_16x16x32_bf16(bk0, aq[0], sc[t], 0, 0, 0); \
                sc[t] = __builtin_amdgcn_mfma_f32_16x16x32_bf16(bk1, aq[1], sc[t], 0, 0, 0); \
            }                                                                            \
        }                                                                                \
        unsigned int pk[4][2];                                                           \
        _Pragma("unroll")                                                                \
        for (int t = 0; t < 4; t++) {                                                    \
            if ((kk) + t * 16 > qmax) { pk[t][0] = 0u; pk[t][1] = 0u; continue; }        \
            float e[4];                                                                  \
            _Pragma("unroll")                                                            \
            for (int r2 = 0; r2 < 4; r2++) e[r2] = __builtin_amdgcn_exp2f(sc[t][r2]);    \
            if ((kk) + t * 16 + 15 > qmin) {                                             \
                _Pragma("unroll")                                                        \
                for (int r2 = 0; r2 < 4; r2++)                                           \
                    if ((kk) + t * 16 + qd * 4 + r2 > qrow) e[r2] = 0.f;                 \
            }                                                                            \
            lsum += (e[0] + e[1]) + (e[2] + e[3]);                                       \
            pk[t][0] = (unsigned int)f2bf(e[0]) | ((unsigned int)f2bf(e[1]) << 16);      \
            pk[t][1] = (unsigned int)f2bf(e[2]) | ((unsigned int)f2bf(e[3]) << 16);      \
        }                                                                                \
        union { unsigned int u[4]; bf16x8 v; } apu0, apu1;                               \
        apu0.u[0] = pk[0][0]; apu0.u[1] = pk[0][1]; apu0.u[2] = pk[1][0]; apu0.u[3] = pk[1][1]; \
        apu1.u[0] = pk[2][0]; apu1.u[1] = pk[2][1]; apu1.u[2] = pk[3][0]; apu1.u[3] = pk[3][1]; \
        _Pragma("unroll")                                                                \
        for (int td = 0; td < 4; td++) {                                                 \
            int voff = (td * 16 + ln) * 64 + psw;                                        \
            bf16x8 av0 = *(const bf16x8*)&VD[voff];                                      \
            bf16x8 av1 = *(const bf16x8*)&VD[voff ^ 32];                                 \
            Oc[td] = __builtin_amdgcn_mfma_f32_16x16x32_bf16(av0, apu0.v, Oc[td], 0, 0, 0); \
            Oc[td] = __builtin_amdgcn_mfma_f32_16x16x32_bf16(av1, apu1.v, Oc[td], 0, 0, 0); \
        }                                                                                \
    }

    FLASH_STAGE(Ks0, Vs0, kstart);
    if (kstart + 64 < kend) FLASH_STAGE(Ks1, Vs1, kstart + 64);

    for (int k0 = kstart; k0 < kend; k0 += 192) {
        // phase 0: tile at k0 from buf0
        FLASH_SYNC(k0 + 64 < kend);
        if (k0 + 128 < kend) FLASH_STAGE(Ks2, Vs2, k0 + 128);
        FLASH_TILE(Ks0, Vs0, k0);
        // phase 1: tile at k0+64 from buf1
        if (k0 + 64 < kend) {
            FLASH_SYNC(k0 + 128 < kend);
            if (k0 + 192 < kend) FLASH_STAGE(Ks0, Vs0, k0 + 192);
            FLASH_TILE(Ks1, Vs1, k0 + 64);
        }
        // phase 2: tile at k0+128 from buf2
        if (k0 + 128 < kend) {
            FLASH_SYNC(k0 + 192 < kend);
            if (k0 + 256 < kend) FLASH_STAGE(Ks1, Vs1, k0 + 256);
            FLASH_TILE(Ks2, Vs2, k0 + 128);
        }
    }
#undef FLASH_STAGE
#undef FLASH_SYNC
#undef FLASH_TILE

    // row-sum butterfly across quads (lanes ln, ln+16, ln+32, ln+48 hold partials)
    lsum += __shfl_xor(lsum, 16);
    lsum += __shfl_xor(lsum, 32);

    if (!heavy) {
        const float inv = 1.0f / lsum;
        // O^T output: lane (qd,ln) reg (td,r) = O[q=ln][d = td*16 + qd*4 + r]
        const int bz = bh >> 4, h = bh & 15;
        const int rowg = qt0 + w * 16 + ln;
        unsigned short* aorow = AO + ((size_t)(bz * 2048 + rowg) << 10) + h * 64 + qd * 4;
#pragma unroll
        for (int td = 0; td < 4; td++) {
            ushort4 o;
            o.x = f2bf(Oc[td][0] * inv);
            o.y = f2bf(Oc[td][1] * inv);
            o.z = f2bf(Oc[td][2] * inv);
            o.w = f2bf(Oc[td][3] * inv);
            *(ushort4*)(aorow + td * 16) = o;
        }
    } else {
        // fp32 partial: P[(bh*8+qi-8)*128 + q][64]; lsum -> Lb[half*32768 + prow]
        float* P = half ? Ph1 : Ph0;
        const int pidx = bh * 8 + (qi - 8);
        const int prow = pidx * 128 + w * 16 + ln;
        float* Pr = P + (size_t)prow * 64 + qd * 4;
#pragma unroll
        for (int td = 0; td < 4; td++)
            *(f32x4*)(Pr + td * 16) = Oc[td];
        if (qd == 0) Lb[half * 32768 + prow] = lsum;

        // last-writer merges this pair (replaces the merge kernel)
        const int bz = bh >> 4, h = bh & 15;
        __threadfence();                              // release: partials visible device-wide
        __syncthreads();                              // all waves' partials written
        if (tid == 0) {
            unsigned int* flagp = (unsigned int*)(AO +
                (((size_t)(bz * 2048 + qt0)) << 10) + h * 64);
            s_last = atomicAdd(flagp, 1u);
        }
        __syncthreads();
        if (s_last == 1u) {                           // second arrival: both halves done
            __threadfence();                          // acquire: see peer's partials
            const int rbase = pidx * 128;
#pragma unroll
            for (int i = 0; i < 2; i++) {
                int c = tid + i * 512;                // 1024 chunks of 8 elems
                int q = c >> 3, d0 = (c & 7) * 8;
                int r = rbase + q;
                float invl = 1.0f / (Lb[r] + Lb[32768 + r]);
                const float* a = Ph0 + (size_t)r * 64 + d0;
                const float* b = Ph1 + (size_t)r * 64 + d0;
                f32x4 x0 = *(const f32x4*)a, x1 = *(const f32x4*)(a + 4);
                f32x4 y0 = *(const f32x4*)b, y1 = *(const f32x4*)(b + 4);
                union { unsigned short us[8]; uint4 v; } pkk;
#pragma unroll
                for (int j = 0; j < 4; j++) {
                    pkk.us[j]     = f2bf((x0[j] + y0[j]) * invl);
                    pkk.us[j + 4] = f2bf((x1[j] + y1[j]) * invl);
                }
                *(uint4*)(AO + (((size_t)(bz * 2048 + qt0 + q)) << 10) + h * 64 + d0) = pkk.v;
            }
        }
    }
}

extern "C" void kernel_launch(void* const* d_in, const int* in_sizes, int n_in,
                              void* d_out, int out_size, void* d_ws, size_t ws_size,
                              hipStream_t stream) {
    const float* x  = (const float*)d_in[0];
    const float* Wq = (const float*)d_in[1];
    const float* Wk = (const float*)d_in[2];
    const float* Wv = (const float*)d_in[3];
    const float* Wo = (const float*)d_in[4];
    float* out = (float*)d_out;

    unsigned short* xb  = (unsigned short*)d_ws;           // 4096*1024
    unsigned short* WT  = xb  + (size_t)4096 * 1024;       // 4*1024*1024
    unsigned short* Qb  = WT  + (size_t)4 * 1024 * 1024;   // Q,K contiguous ([B][H][S][64])
    unsigned short* Kb  = Qb  + (size_t)4096 * 1024;
    unsigned short* Vb  = Kb  + (size_t)4096 * 1024;       // dead slot -> half0 partials
    unsigned short* Vpb = Vb  + (size_t)4096 * 1024;       // Vp [B][H][64][S] permuted
    unsigned short* AO  = Vpb + (size_t)4096 * 1024;

    float* Ph0 = (float*)Vb;   // 8 MB: heavy half0 fp32 partial O (exactly 2M floats)
    float* Ph1 = (float*)xb;   // 8 MB: heavy half1 (xb dead after gemm_qkv)
    float* Lb  = (float*)WT;   // 256 KB: lsum partials (Wq^T region dead after gemm_qkv)

    prep<<<dim3(5120), 256, 0, stream>>>(x, Wq, Wk, Wv, Wo, xb, WT, AO);
    gemm_qkv<<<dim3(768), 256, 0, stream>>>(xb, WT, Qb, Vpb);
    flash<<<dim3(768), 512, 0, stream>>>(Qb, Kb, Vpb, AO, Ph0, Ph1, Lb);
    gemm_o<<<dim3(256), 256, 0, stream>>>(AO, WT + (size_t)3 * 1024 * 1024, out);
}

// Round 13
// 163.722 us; speedup vs baseline: 1.8977x; 1.8977x over previous
//
#include <hip/hip_runtime.h>

// StandardAttention: B=2,S=2048,D=1024,H=16,DQK=DV=64. fp32 in/out, bf16 MFMA inside.
// Workspace layout (56 MB):
//   xb  [4096][1024] bf16           8 MB   (dead after gemm_qkv -> heavy half1 fp32 partials Ph1)
//   WT  [4][1024][1024] bf16 (W^T)  8 MB   (z=0 dead after gemm_qkv -> first 256KB = lsum Lb)
//   Q,K [B][H][S][64] bf16          16 MB  (Q pre-scaled by 0.125*log2(e))
//   Vb  (unused slot)               8 MB   (heavy half0 fp32 partials Ph0)
//   Vp  [B][H][64][S] bf16          8 MB
//   AO  [B][S][1024] bf16           8 MB
//
// R2: BK=64. R7: split-K heavy flash + merge. R8: static-dbuf 1-barrier GEMMs.
// R10: prep fusion. R11: flash counted-vmcnt 3-buffer pipeline (166.8us).
// R12 post-mortem (310us, REVERTED): last-writer-merge put a device-scope
//   __threadfence (= L2 writeback for cross-XCD visibility) + contended atomic in 512
//   heavy-block epilogues -> serialized fence storms (MfmaUtil 3.5%, all pipes idle).
//   Cross-XCD fences are priced per-fence; the separate merge kernel's single kernel
//   boundary is the correct amortization. R13 = exact R11 restore.

typedef float  f32x4  __attribute__((ext_vector_type(4)));
typedef __bf16 bf16x8 __attribute__((ext_vector_type(8)));

__device__ __forceinline__ unsigned short f2bf(float f) {
    __bf16 h = (__bf16)f;
    return __builtin_bit_cast(unsigned short, h);
}

// async global->LDS, 16B per lane; lds base wave-uniform (HW: base + lane*16)
__device__ __forceinline__ void gld16(unsigned short* lds, const unsigned short* g) {
    __builtin_amdgcn_global_load_lds(
        (const __attribute__((address_space(1))) void*)g,
        (__attribute__((address_space(3))) void*)lds, 16, 0, 0);
}

// ---------------- prep: castx (blocks 0..4095) + wtrans (blocks 4096..5119) -------------
__global__ __launch_bounds__(256) void prep(const float* __restrict__ x,
                                            const float* __restrict__ W0,
                                            const float* __restrict__ W1,
                                            const float* __restrict__ W2,
                                            const float* __restrict__ W3,
                                            unsigned short* __restrict__ xb,
                                            unsigned short* __restrict__ WT) {
    __shared__ float T[64][65];
    const int blk = blockIdx.x;
    const int tid = threadIdx.x;
    if (blk < 4096) {
        size_t i = ((size_t)blk * 256 + tid) * 4;
        float4 v = *(const float4*)(x + i);
        ushort4 o;
        o.x = f2bf(v.x); o.y = f2bf(v.y); o.z = f2bf(v.z); o.w = f2bf(v.w);
        *(ushort4*)(xb + i) = o;
        return;
    }
    const int t = blk - 4096;
    const int z = t >> 8;
    const int k0 = ((t >> 4) & 15) * 64, n0 = (t & 15) * 64;
    const float* W = (z == 0) ? W0 : (z == 1) ? W1 : (z == 2) ? W2 : W3;
#pragma unroll
    for (int i = 0; i < 4; i++) {
        int c = tid + i * 256;
        int r = c >> 4, col = (c & 15) * 4;
        float4 v = *(const float4*)(W + (size_t)(k0 + r) * 1024 + n0 + col);
        T[r][col] = v.x; T[r][col + 1] = v.y; T[r][col + 2] = v.z; T[r][col + 3] = v.w;
    }
    __syncthreads();
    unsigned short* out = WT + (size_t)z * 1024 * 1024;
#pragma unroll
    for (int i = 0; i < 2; i++) {
        int c = tid + i * 256;
        int nr = c >> 3, koff = (c & 7) * 8;
        union { unsigned short us[8]; uint4 v; } pk;
#pragma unroll
        for (int j = 0; j < 8; j++) pk.us[j] = f2bf(T[koff + j][nr]);
        *(uint4*)(out + (size_t)(n0 + nr) * 1024 + k0 + koff) = pk.v;
    }
}

// ---------------- QKV GEMM: [4096][1024] x WT^T per z; BK=64, static dbuf, 1 barrier ----
__global__ __launch_bounds__(256) void gemm_qkv(const unsigned short* __restrict__ A,
                                                const unsigned short* __restrict__ WTall,
                                                unsigned short* __restrict__ outq,
                                                unsigned short* __restrict__ Vp) {
    __shared__ unsigned short As0[128 * 64];
    __shared__ unsigned short Bs0[128 * 64];
    __shared__ unsigned short As1[128 * 64];
    __shared__ unsigned short Bs1[128 * 64];
    const int tid = threadIdx.x;
    const int w = tid >> 6, lane = tid & 63, quad = lane >> 4, ln = lane & 15;

    const int blk = blockIdx.x;
    const int n0 = ((blk >> 3) & 7) * 128;
    const int g  = ((blk >> 6) << 3) | (blk & 7);   // 0..95 = z*32+m
    const int z  = g >> 5;
    const int m0 = (g & 31) * 128;

    const unsigned short* BT = WTall + (size_t)z * (1024 * 1024);
    const float scl = (z == 0) ? 0.180336878f : 1.0f;
    const bool swp = (z < 2);

    const int lr8 = lane >> 3;                      // row within 8-row staging group
    const int lc8 = ((lane & 7) ^ lr8) * 8;         // XOR-swizzled source chunk (elems)
    const int fsw = (quad ^ (ln & 7)) * 8;          // swizzled frag-read chunk (elems)

    const f32x4 z4 = {0.f, 0.f, 0.f, 0.f};
    f32x4 acc[4][4];
#pragma unroll
    for (int i = 0; i < 4; i++)
#pragma unroll
        for (int j = 0; j < 4; j++) acc[i][j] = z4;

    const int wm = (w & 1) * 64, wn = (w >> 1) * 64;
    const int Rb = w * 32;                          // staging row base for this wave

#define QKV_STAGE(Ad, Bd, kk)                                                              \
    {                                                                                      \
        _Pragma("unroll")                                                                  \
        for (int s = 0; s < 4; s++) {                                                      \
            gld16(Ad + (Rb + s * 8) * 64, A  + (size_t)(m0 + Rb + s * 8 + lr8) * 1024 + (kk) + lc8); \
            gld16(Bd + (Rb + s * 8) * 64, BT + (size_t)(n0 + Rb + s * 8 + lr8) * 1024 + (kk) + lc8); \
        }                                                                                  \
    }

#define QKV_COMPUTE(Ad, Bd)                                                                \
    {                                                                                      \
        _Pragma("unroll")                                                                  \
        for (int ks = 0; ks < 2; ks++) {                                                   \
            const int co = fsw ^ (ks * 32);                                                \
            bf16x8 af[4], bfr[4];                                                          \
            _Pragma("unroll")                                                              \
            for (int t = 0; t < 4; t++)                                                    \
                af[t] = *(const bf16x8*)&Ad[(wm + t * 16 + ln) * 64 + co];                 \
            _Pragma("unroll")                                                              \
            for (int t = 0; t < 4; t++)                                                    \
                bfr[t] = *(const bf16x8*)&Bd[(wn + t * 16 + ln) * 64 + co];                \
            if (swp) {                                                                     \
                _Pragma("unroll")                                                          \
                for (int tm = 0; tm < 4; tm++)                                             \
                    _Pragma("unroll")                                                      \
                    for (int tn = 0; tn < 4; tn++)                                         \
                        acc[tm][tn] = __builtin_amdgcn_mfma_f32_16x16x32_bf16(             \
                            bfr[tn], af[tm], acc[tm][tn], 0, 0, 0);                        \
            } else {                                                                       \
                _Pragma("unroll")                                                          \
                for (int tm = 0; tm < 4; tm++)                                             \
                    _Pragma("unroll")                                                      \
                    for (int tn = 0; tn < 4; tn++)                                         \
                        acc[tm][tn] = __builtin_amdgcn_mfma_f32_16x16x32_bf16(             \
                            af[tm], bfr[tn], acc[tm][tn], 0, 0, 0);                        \
            }                                                                              \
        }                                                                                  \
    }

    QKV_STAGE(As0, Bs0, 0);
    for (int k0 = 0; k0 < 1024; k0 += 128) {
        __syncthreads();                          // publishes buf0 (drains its staging)
        if (k0 + 64 < 1024) QKV_STAGE(As1, Bs1, k0 + 64);
        QKV_COMPUTE(As0, Bs0);
        __syncthreads();                          // publishes buf1
        if (k0 + 128 < 1024) QKV_STAGE(As0, Bs0, k0 + 128);
        if (k0 + 64 < 1024) QKV_COMPUTE(As1, Bs1);
    }
#undef QKV_STAGE
#undef QKV_COMPUTE

    if (swp) {
        // acc[tm][tn] = D^T block: lane ln -> s-row, regs -> 4 consecutive d
#pragma unroll
        for (int tm = 0; tm < 4; tm++)
#pragma unroll
            for (int tn = 0; tn < 4; tn++) {
                int mg = m0 + wm + tm * 16 + ln;            // s row (global among 4096)
                int nb = n0 + wn + tn * 16 + quad * 4;      // d col base
                int b = mg >> 11, s = mg & 2047, h = nb >> 6, dd = nb & 63;
                ushort4 o;
                o.x = f2bf(acc[tm][tn][0] * scl);
                o.y = f2bf(acc[tm][tn][1] * scl);
                o.z = f2bf(acc[tm][tn][2] * scl);
                o.w = f2bf(acc[tm][tn][3] * scl);
                size_t zoff = (size_t)z * (4096 * 1024);
                *(ushort4*)(outq + zoff + (((size_t)(b * 16 + h) * 2048 + s) << 6) + dd) = o;
            }
    } else {
        // V: normal D block: lane ln -> d, regs -> 4 consecutive s = one Vp permute group
#pragma unroll
        for (int tm = 0; tm < 4; tm++)
#pragma unroll
            for (int tn = 0; tn < 4; tn++) {
                int mg = m0 + wm + tm * 16 + quad * 4;      // s base (r spans 4)
                int ng = n0 + wn + tn * 16 + ln;            // d
                int b = mg >> 11, h = ng >> 6, dd = ng & 63;
                int sblk = (mg & 2047) & ~63;
                int cb = tm >> 1, t16 = tm & 1;
                int pp = cb * 32 + quad * 8 + t16 * 4;
                ushort4 o;
                o.x = f2bf(acc[tm][tn][0]);
                o.y = f2bf(acc[tm][tn][1]);
                o.z = f2bf(acc[tm][tn][2]);
                o.w = f2bf(acc[tm][tn][3]);
                *(ushort4*)(Vp + ((size_t)(b * 16 + h) * 64 + dd) * 2048 + sblk + pp) = o;
            }
    }
}

// ---------------- out-proj GEMM: out[4096][1024] = AO @ WoT^T, 128x128, static dbuf ----
__global__ __launch_bounds__(256) void gemm_o(const unsigned short* __restrict__ A,
                                              const unsigned short* __restrict__ BT,
                                              float* __restrict__ outf) {
    __shared__ unsigned short As0[128 * 64];
    __shared__ unsigned short Bs0[128 * 64];
    __shared__ unsigned short As1[128 * 64];
    __shared__ unsigned short Bs1[128 * 64];
    const int tid = threadIdx.x;
    const int w = tid >> 6, lane = tid & 63, quad = lane >> 4, ln = lane & 15;

    const int blk = blockIdx.x;
    const int n0 = ((blk >> 3) & 7) * 128;
    const int m0 = (((blk >> 6) << 3) | (blk & 7)) * 128;   // 0..31 tiles

    const int lr8 = lane >> 3;
    const int lc8 = ((lane & 7) ^ lr8) * 8;
    const int fsw = (quad ^ (ln & 7)) * 8;

    const f32x4 z4 = {0.f, 0.f, 0.f, 0.f};
    f32x4 acc[4][4];
#pragma unroll
    for (int i = 0; i < 4; i++)
#pragma unroll
        for (int j = 0; j < 4; j++) acc[i][j] = z4;

    const int wm = (w & 1) * 64, wn = (w >> 1) * 64;
    const int Rb = w * 32;

#define O_STAGE(Ad, Bd, kk)                                                                \
    {                                                                                      \
        _Pragma("unroll")                                                                  \
        for (int s = 0; s < 4; s++) {                                                      \
            gld16(Ad + (Rb + s * 8) * 64, A  + (size_t)(m0 + Rb + s * 8 + lr8) * 1024 + (kk) + lc8); \
            gld16(Bd + (Rb + s * 8) * 64, BT + (size_t)(n0 + Rb + s * 8 + lr8) * 1024 + (kk) + lc8); \
        }                                                                                  \
    }

#define O_COMPUTE(Ad, Bd)                                                                  \
    {                                                                                      \
        _Pragma("unroll")                                                                  \
        for (int ks = 0; ks < 2; ks++) {                                                   \
            const int co = fsw ^ (ks * 32);                                                \
            bf16x8 af[4], bfr[4];                                                          \
            _Pragma("unroll")                                                              \
            for (int t = 0; t < 4; t++)                                                    \
                af[t] = *(const bf16x8*)&Ad[(wm + t * 16 + ln) * 64 + co];                 \
            _Pragma("unroll")                                                              \
            for (int t = 0; t < 4; t++)                                                    \
                bfr[t] = *(const bf16x8*)&Bd[(wn + t * 16 + ln) * 64 + co];                \
            _Pragma("unroll")                                                              \
            for (int tm = 0; tm < 4; tm++)                                                 \
                _Pragma("unroll")                                                          \
                for (int tn = 0; tn < 4; tn++)                                             \
                    acc[tm][tn] = __builtin_amdgcn_mfma_f32_16x16x32_bf16(                 \
                        bfr[tn], af[tm], acc[tm][tn], 0, 0, 0);                            \
        }                                                                                  \
    }

    O_STAGE(As0, Bs0, 0);
    for (int k0 = 0; k0 < 1024; k0 += 128) {
        __syncthreads();
        if (k0 + 64 < 1024) O_STAGE(As1, Bs1, k0 + 64);
        O_COMPUTE(As0, Bs0);
        __syncthreads();
        if (k0 + 128 < 1024) O_STAGE(As0, Bs0, k0 + 128);
        if (k0 + 64 < 1024) O_COMPUTE(As1, Bs1);
    }
#undef O_STAGE
#undef O_COMPUTE

    // D^T blocks: lane ln -> output row, reg quad -> 4 consecutive cols -> float4 stores
#pragma unroll
    for (int tm = 0; tm < 4; tm++)
#pragma unroll
        for (int tn = 0; tn < 4; tn++) {
            int mg = m0 + wm + tm * 16 + ln;
            int nb = n0 + wn + tn * 16 + quad * 4;
            *(f32x4*)(outf + (size_t)mg * 1024 + nb) = acc[tm][tn];
        }
}

// ---------------- flash attention (split-K, 8 waves, counted-vmcnt 3-buffer) ------------
// Slot decode: bh = blk&31, s = blk>>5 (0..23).
//   s<8:    light q-tile qi=s, full k range [0,(qi+1)*128), normalize, write AO.
//   s>=8:   heavy q-tile qi=15-((s-8)&7), half=(s-8)>>3; fp32 partials to ws (merge later).
// CU triple = 34 tiles for every CU; max serial chain 16 tiles.
// Pipeline: 3 staging buffers; per tile: counted s_waitcnt vmcnt(2) (stage t done,
// stage t+1 stays IN FLIGHT across the barrier) + raw s_barrier + sched_barrier(0),
// then issue stage t+2, then compute tile t. vmcnt(0) only at the final tile.
__global__ __launch_bounds__(512, 4) void flash(const unsigned short* __restrict__ Qb,
                                                const unsigned short* __restrict__ Kb,
                                                const unsigned short* __restrict__ Vpb,
                                                unsigned short* __restrict__ AO,
                                                float* __restrict__ Ph0,
                                                float* __restrict__ Ph1,
                                                float* __restrict__ Lb) {
    __shared__ __align__(16) unsigned short Ks0[64 * 64];
    __shared__ __align__(16) unsigned short Vs0[64 * 64];
    __shared__ __align__(16) unsigned short Ks1[64 * 64];
    __shared__ __align__(16) unsigned short Vs1[64 * 64];
    __shared__ __align__(16) unsigned short Ks2[64 * 64];
    __shared__ __align__(16) unsigned short Vs2[64 * 64];
    const int tid = threadIdx.x, w = tid >> 6, lane = tid & 63;
    const int qd = lane >> 4, ln = lane & 15;
    const int lr = lane >> 3;                  // row-within-8 for staging
    const int lchunk = (lane & 7) ^ lr;        // swizzled source 16B-chunk
    const int psw = (qd ^ (ln & 7)) * 8;       // swizzled read chunk offset (elems)

    const int blk = blockIdx.x;
    const int bh = blk & 31;
    const int s  = blk >> 5;                   // 0..23
    int qi, kstart, kend, half;
    bool heavy;
    if (s < 8) {
        qi = s; kstart = 0; kend = (qi + 1) * 128; half = 0; heavy = false;
    } else {
        int t = s - 8; half = t >> 3; qi = 15 - (t & 7); heavy = true;
        int mid = (qi + 1) * 64;
        kstart = half ? mid : 0;
        kend   = half ? (qi + 1) * 128 : mid;
    }
    const int qt0 = qi * 128;

    const unsigned short* Kg = Kb  + (size_t)bh * 2048 * 64;
    const unsigned short* Vg = Vpb + (size_t)bh * 64 * 2048;

    // Q fragment (B-operand of S^T MFMA): lane ln holds Q[qt0+w*16+ln][qd*8+j]
    bf16x8 aq[2];
    {
        const unsigned short* Qrow = Qb + ((size_t)bh * 2048 + qt0 + w * 16 + ln) * 64 + qd * 8;
        aq[0] = *(const bf16x8*)(Qrow);
        aq[1] = *(const bf16x8*)(Qrow + 32);
    }

    const f32x4 z4 = {0.f, 0.f, 0.f, 0.f};
    f32x4 Oc[4];
#pragma unroll
    for (int td = 0; td < 4; td++) Oc[td] = z4;
    float lsum = 0.f;

    const int qrow = qt0 + w * 16 + ln;   // lane's q row (S^T: q indexed by ln)
    const int qmin = qt0 + w * 16;
    const int qmax = qmin + 15;

    // stage(KD,VD, kk): wave w fills K rows [w*8,w*8+8) and Vp d-rows [w*8,w*8+8) (2 gld16)
#define FLASH_STAGE(KD, VD, kk)                                                          \
    {                                                                                    \
        const unsigned short* kg = Kg + (size_t)((kk) + w * 8 + lr) * 64 + lchunk * 8;   \
        gld16(&KD[(w * 8) * 64], kg);                                                    \
        const unsigned short* vg = Vg + (size_t)(w * 8 + lr) * 2048 + (kk) + lchunk * 8; \
        gld16(&VD[(w * 8) * 64], vg);                                                    \
    }

    // counted-vmcnt barrier: stage(t) complete; stage(t+1) (2 loads) may stay in flight
#define FLASH_SYNC(more)                                                                 \
    {                                                                                    \
        if (more) { asm volatile("s_waitcnt vmcnt(2)" ::: "memory"); }                   \
        else      { asm volatile("s_waitcnt vmcnt(0)" ::: "memory"); }                   \
        __builtin_amdgcn_s_barrier();                                                    \
        __builtin_amdgcn_sched_barrier(0);                                               \
    }

    // full tile compute from buffers (KD,VD) at k-offset kk (wave-uniform skip)
#define FLASH_TILE(KD, VD, kk)                                                           \
    if ((kk) <= qmax) {                                                                  \
        f32x4 sc[4];                                                                     \
        _Pragma("unroll")                                                                \
        for (int t = 0; t < 4; t++) {                                                    \
            sc[t] = z4;                                                                  \
            if ((kk) + t * 16 <= qmax) {                                                 \
                int off = (t * 16 + ln) * 64 + psw;                                      \
                bf16x8 bk0 = *(const bf16x8*)&KD[off];                                   \
                bf16x8 bk1 = *(const bf16x8*)&KD[off ^ 32];                              \
                sc[t] = __builtin_amdgcn_mfma_f32_16x16x32_bf16(bk0, aq[0], sc[t], 0, 0, 0); \
                sc[t] = __builtin_amdgcn_mfma_f32_16x16x32_bf16(bk1, aq[1], sc[t], 0, 0, 0); \
            }                                                                            \
        }                                                                                \
        unsigned int pk[4][2];                                                           \
        _Pragma("unroll")                                                                \
        for (int t = 0; t < 4; t++) {                                                    \
            if ((kk) + t * 16 > qmax) { pk[t][0] = 0u; pk[t][1] = 0u; continue; }        \
            float e[4];                                                                  \
            _Pragma("unroll")                                                            \
            for (int r2 = 0; r2 < 4; r2++) e[r2] = __builtin_amdgcn_exp2f(sc[t][r2]);    \
            if ((kk) + t * 16 + 15 > qmin) {                                             \
                _Pragma("unroll")                                                        \
                for (int r2 = 0; r2 < 4; r2++)                                           \
                    if ((kk) + t * 16 + qd * 4 + r2 > qrow) e[r2] = 0.f;                 \
            }                                                                            \
            lsum += (e[0] + e[1]) + (e[2] + e[3]);                                       \
            pk[t][0] = (unsigned int)f2bf(e[0]) | ((unsigned int)f2bf(e[1]) << 16);      \
            pk[t][1] = (unsigned int)f2bf(e[2]) | ((unsigned int)f2bf(e[3]) << 16);      \
        }                                                                                \
        union { unsigned int u[4]; bf16x8 v; } apu0, apu1;                               \
        apu0.u[0] = pk[0][0]; apu0.u[1] = pk[0][1]; apu0.u[2] = pk[1][0]; apu0.u[3] = pk[1][1]; \
        apu1.u[0] = pk[2][0]; apu1.u[1] = pk[2][1]; apu1.u[2] = pk[3][0]; apu1.u[3] = pk[3][1]; \
        _Pragma("unroll")                                                                \
        for (int td = 0; td < 4; td++) {                                                 \
            int voff = (td * 16 + ln) * 64 + psw;                                        \
            bf16x8 av0 = *(const bf16x8*)&VD[voff];                                      \
            bf16x8 av1 = *(const bf16x8*)&VD[voff ^ 32];                                 \
            Oc[td] = __builtin_amdgcn_mfma_f32_16x16x32_bf16(av0, apu0.v, Oc[td], 0, 0, 0); \
            Oc[td] = __builtin_amdgcn_mfma_f32_16x16x32_bf16(av1, apu1.v, Oc[td], 0, 0, 0); \
        }                                                                                \
    }

    FLASH_STAGE(Ks0, Vs0, kstart);
    if (kstart + 64 < kend) FLASH_STAGE(Ks1, Vs1, kstart + 64);

    for (int k0 = kstart; k0 < kend; k0 += 192) {
        // phase 0: tile at k0 from buf0
        FLASH_SYNC(k0 + 64 < kend);
        if (k0 + 128 < kend) FLASH_STAGE(Ks2, Vs2, k0 + 128);
        FLASH_TILE(Ks0, Vs0, k0);
        // phase 1: tile at k0+64 from buf1
        if (k0 + 64 < kend) {
            FLASH_SYNC(k0 + 128 < kend);
            if (k0 + 192 < kend) FLASH_STAGE(Ks0, Vs0, k0 + 192);
            FLASH_TILE(Ks1, Vs1, k0 + 64);
        }
        // phase 2: tile at k0+128 from buf2
        if (k0 + 128 < kend) {
            FLASH_SYNC(k0 + 192 < kend);
            if (k0 + 256 < kend) FLASH_STAGE(Ks1, Vs1, k0 + 256);
            FLASH_TILE(Ks2, Vs2, k0 + 128);
        }
    }
#undef FLASH_STAGE
#undef FLASH_SYNC
#undef FLASH_TILE

    // row-sum butterfly across quads (lanes ln, ln+16, ln+32, ln+48 hold partials)
    lsum += __shfl_xor(lsum, 16);
    lsum += __shfl_xor(lsum, 32);

    if (!heavy) {
        const float inv = 1.0f / lsum;
        // O^T output: lane (qd,ln) reg (td,r) = O[q=ln][d = td*16 + qd*4 + r]
        const int bz = bh >> 4, h = bh & 15;
        const int rowg = qt0 + w * 16 + ln;
        unsigned short* aorow = AO + ((size_t)(bz * 2048 + rowg) << 10) + h * 64 + qd * 4;
#pragma unroll
        for (int td = 0; td < 4; td++) {
            ushort4 o;
            o.x = f2bf(Oc[td][0] * inv);
            o.y = f2bf(Oc[td][1] * inv);
            o.z = f2bf(Oc[td][2] * inv);
            o.w = f2bf(Oc[td][3] * inv);
            *(ushort4*)(aorow + td * 16) = o;
        }
    } else {
        // fp32 partial: P[(bh*8+qi-8)*128 + q][64]; lsum -> Lb[half*32768 + prow]
        float* P = half ? Ph1 : Ph0;
        const int prow = ((bh * 8 + (qi - 8)) * 128) + w * 16 + ln;
        float* Pr = P + (size_t)prow * 64 + qd * 4;
#pragma unroll
        for (int td = 0; td < 4; td++)
            *(f32x4*)(Pr + td * 16) = Oc[td];
        if (qd == 0) Lb[half * 32768 + prow] = lsum;
    }
}

// ---------------- merge heavy split-K partials -> AO ------------------------------------
// 32768 rows x 64 d; thread handles 8 d. O = (P0+P1)/(l0+l1), bf16, into AO heavy rows.
__global__ __launch_bounds__(256) void merge(const float* __restrict__ P0,
                                             const float* __restrict__ P1,
                                             const float* __restrict__ Lb,
                                             unsigned short* __restrict__ AO) {
    const int idx = blockIdx.x * 256 + threadIdx.x;   // 0..262143
    const int d0 = (idx & 7) * 8;
    const int row = idx >> 3;                          // (bh*8+qi8)*128 + q
    const float inv = 1.0f / (Lb[row] + Lb[32768 + row]);
    const float* a = P0 + (size_t)row * 64 + d0;
    const float* b = P1 + (size_t)row * 64 + d0;
    f32x4 x0 = *(const f32x4*)a, x1 = *(const f32x4*)(a + 4);
    f32x4 y0 = *(const f32x4*)b, y1 = *(const f32x4*)(b + 4);
    union { unsigned short us[8]; uint4 v; } pk;
#pragma unroll
    for (int j = 0; j < 4; j++) {
        pk.us[j]     = f2bf((x0[j] + y0[j]) * inv);
        pk.us[j + 4] = f2bf((x1[j] + y1[j]) * inv);
    }
    const int bh = row >> 10, qi8 = (row >> 7) & 7, q = row & 127;
    const int bz = bh >> 4, h = bh & 15;
    const int rowg = (qi8 + 8) * 128 + q;
    *(uint4*)(AO + ((size_t)(bz * 2048 + rowg) << 10) + h * 64 + d0) = pk.v;
}

extern "C" void kernel_launch(void* const* d_in, const int* in_sizes, int n_in,
                              void* d_out, int out_size, void* d_ws, size_t ws_size,
                              hipStream_t stream) {
    const float* x  = (const float*)d_in[0];
    const float* Wq = (const float*)d_in[1];
    const float* Wk = (const float*)d_in[2];
    const float* Wv = (const float*)d_in[3];
    const float* Wo = (const float*)d_in[4];
    float* out = (float*)d_out;

    unsigned short* xb  = (unsigned short*)d_ws;           // 4096*1024
    unsigned short* WT  = xb  + (size_t)4096 * 1024;       // 4*1024*1024
    unsigned short* Qb  = WT  + (size_t)4 * 1024 * 1024;   // Q,K contiguous ([B][H][S][64])
    unsigned short* Kb  = Qb  + (size_t)4096 * 1024;
    unsigned short* Vb  = Kb  + (size_t)4096 * 1024;       // dead slot -> half0 partials
    unsigned short* Vpb = Vb  + (size_t)4096 * 1024;       // Vp [B][H][64][S] permuted
    unsigned short* AO  = Vpb + (size_t)4096 * 1024;

    float* Ph0 = (float*)Vb;   // 8 MB: heavy half0 fp32 partial O (exactly 2M floats)
    float* Ph1 = (float*)xb;   // 8 MB: heavy half1 (xb dead after gemm_qkv)
    float* Lb  = (float*)WT;   // 256 KB: lsum partials (Wq^T region dead after gemm_qkv)

    prep<<<dim3(5120), 256, 0, stream>>>(x, Wq, Wk, Wv, Wo, xb, WT);
    gemm_qkv<<<dim3(768), 256, 0, stream>>>(xb, WT, Qb, Vpb);
    flash<<<dim3(768), 512, 0, stream>>>(Qb, Kb, Vpb, AO, Ph0, Ph1, Lb);
    merge<<<dim3(1024), 256, 0, stream>>>(Ph0, Ph1, Lb, AO);
    gemm_o<<<dim3(256), 256, 0, stream>>>(AO, WT + (size_t)3 * 1024 * 1024, out);
}